// Round 2
// baseline (401.364 us; speedup 1.0000x reference)
//
#include <hip/hip_runtime.h>
#include <hip/hip_bf16.h>

typedef __attribute__((ext_vector_type(4))) float f32x4;
typedef __attribute__((ext_vector_type(8))) short s16x8;

__device__ __forceinline__ ushort f2bf(float f){
  union { float f; unsigned u; } x; x.f = f;
  unsigned r = x.u + 0x7fffu + ((x.u >> 16) & 1u);
  return (ushort)(r >> 16);
}
__device__ __forceinline__ float bf2f(ushort h){
  union { unsigned u; float f; } x; x.u = ((unsigned)h) << 16;
  return x.f;
}

// ---------------------------------------------------------------------------
// Kernel A: Q/K/V 1x1-conv projections, fp32 weights (no quantization).
//  lane = pixel (coalesced x loads), wave w = outputs [w*16, w*16+16).
//  Q,K written as bf16 hi+lo pairs in [n][o] layout (via LDS transpose);
//  V written bf16 in [o][n] layout (coalesced directly).
// ---------------------------------------------------------------------------
__global__ __launch_bounds__(256) void proj_qkv(
    const float* __restrict__ xr, const float* __restrict__ xi,
    const float* __restrict__ wq, const float* __restrict__ bq,
    const float* __restrict__ wk, const float* __restrict__ bk,
    const float* __restrict__ wv, const float* __restrict__ bv,
    ushort* __restrict__ Qh, ushort* __restrict__ Ql,
    ushort* __restrict__ Kh, ushort* __restrict__ Kl,
    ushort* __restrict__ Vt)
{
  __shared__ ushort tA[64][68];   // padded rows: stride 68 ushorts
  __shared__ ushort tB[64][68];
  const int tid  = threadIdx.x;
  const int b    = blockIdx.x >> 6;
  const int n0   = (blockIdx.x & 63) << 6;
  const int lane = tid & 63;
  const int wo   = __builtin_amdgcn_readfirstlane(tid >> 6) << 4;  // o-base, SGPR

  const float* xrb = xr + (size_t)b*128*4096 + n0 + lane;
  const float* xib = xi + (size_t)b*128*4096 + n0 + lane;

  float aq[16], ak[16], av[16];
  #pragma unroll
  for (int oo=0;oo<16;++oo){ aq[oo]=0.f; ak[oo]=0.f; av[oo]=0.f; }

  for (int c = 0; c < 128; ++c){
    float rv = xrb[c*4096];                  // 256B coalesced per wave
    float iv = xib[c*4096];
    #pragma unroll
    for (int oo=0;oo<16;++oo){
      float wqv = wq[(wo+oo)*128 + c];       // wave-uniform -> s_load, fp32
      float wkv = wk[(wo+oo)*128 + c];
      float wvv = wv[(wo+oo)*128 + c];
      aq[oo] = fmaf(wqv, rv, aq[oo]);
      ak[oo] = fmaf(wkv, iv, ak[oo]);
      av[oo] = fmaf(wvv, iv, av[oo]);
    }
  }

  // V: direct coalesced [o][n] stores
  #pragma unroll
  for (int oo=0;oo<16;++oo){
    float v = av[oo] + bv[wo+oo];
    Vt[((size_t)(b*64 + wo+oo))*4096 + n0 + lane] = f2bf(v);
  }

  const int s_w = lane & 31;
  // ---- Q: stage hi/lo into LDS (transposed), then vectorized stores ----
  #pragma unroll
  for (int oo=0;oo<16;++oo){
    float q = aq[oo] + bq[wo+oo];
    ushort qhi = f2bf(q);
    tA[lane][(wo+oo) ^ s_w] = qhi;
    tB[lane][(wo+oo) ^ s_w] = f2bf(q - bf2f(qhi));
  }
  __syncthreads();
  {
    int n = tid >> 2, c0 = (tid & 3) << 4, s = n & 31;
    ushort* dh = Qh + ((size_t)(b*4096 + n0 + n))*64 + c0;
    ushort* dl = Ql + ((size_t)(b*4096 + n0 + n))*64 + c0;
    #pragma unroll
    for (int j=0;j<16;j+=8){
      s16x8 vh, vl;
      #pragma unroll
      for (int e=0;e<8;++e){
        vh[e] = (short)tA[n][(c0+j+e) ^ s];
        vl[e] = (short)tB[n][(c0+j+e) ^ s];
      }
      *(s16x8*)(dh + j) = vh;
      *(s16x8*)(dl + j) = vl;
    }
  }
  __syncthreads();
  // ---- K: same dance ----
  #pragma unroll
  for (int oo=0;oo<16;++oo){
    float k = ak[oo] + bk[wo+oo];
    ushort khi = f2bf(k);
    tA[lane][(wo+oo) ^ s_w] = khi;
    tB[lane][(wo+oo) ^ s_w] = f2bf(k - bf2f(khi));
  }
  __syncthreads();
  {
    int n = tid >> 2, c0 = (tid & 3) << 4, s = n & 31;
    ushort* dh = Kh + ((size_t)(b*4096 + n0 + n))*64 + c0;
    ushort* dl = Kl + ((size_t)(b*4096 + n0 + n))*64 + c0;
    #pragma unroll
    for (int j=0;j<16;j+=8){
      s16x8 vh, vl;
      #pragma unroll
      for (int e=0;e<8;++e){
        vh[e] = (short)tA[n][(c0+j+e) ^ s];
        vl[e] = (short)tB[n][(c0+j+e) ^ s];
      }
      *(s16x8*)(dh + j) = vh;
      *(s16x8*)(dl + j) = vl;
    }
  }
}

// ---------------------------------------------------------------------------
// Kernel B: flash attention with hi/lo split QK^T (fp32-accurate corr).
//  Block = (b, 64-row Q tile), 4 waves x 16 rows. mfma_f32_16x16x32_bf16.
//  C/D layout: col=lane&15, row=(lane>>4)*4+reg.
// ---------------------------------------------------------------------------
__global__ __launch_bounds__(256) void flash_attn(
    const ushort* __restrict__ Qh, const ushort* __restrict__ Ql,
    const ushort* __restrict__ Kh, const ushort* __restrict__ Kl,
    const ushort* __restrict__ Vt, float* __restrict__ O)
{
  __shared__ ushort p_lds[4][16*64];     // per-wave 16x64 bf16 P tile, swizzled
  const int tid  = threadIdx.x;
  const int b    = blockIdx.x >> 6;
  const int qt   = blockIdx.x & 63;
  const int lane = tid & 63;
  const int w    = tid >> 6;
  const int l15  = lane & 15;
  const int g    = lane >> 4;
  const int qrow = qt*64 + w*16;

  const size_t qoff = ((size_t)(b*4096 + qrow + l15))*64 + g*8;
  s16x8 qh0 = *(const s16x8*)(Qh + qoff);
  s16x8 qh1 = *(const s16x8*)(Qh + qoff + 32);
  s16x8 ql0 = *(const s16x8*)(Ql + qoff);
  s16x8 ql1 = *(const s16x8*)(Ql + qoff + 32);

  const ushort* Khb = Kh + (size_t)b*4096*64;
  const ushort* Klb = Kl + (size_t)b*4096*64;
  const ushort* Vb  = Vt + (size_t)b*64*4096;

  f32x4 o_acc[4];
  #pragma unroll
  for (int ot=0;ot<4;++ot) o_acc[ot] = (f32x4){0.f,0.f,0.f,0.f};
  float m_run[4], l_run[4];
  #pragma unroll
  for (int r=0;r<4;++r){ m_run[r] = -1e30f; l_run[r] = 0.f; }

  ushort* pw = p_lds[w];

  for (int kv = 0; kv < 4096; kv += 64){
    // ---- S = Q K^T (16 x 64), hi/lo split ----
    f32x4 s[4];
    #pragma unroll
    for (int ct=0; ct<4; ++ct){
      size_t koff = ((size_t)(kv + ct*16 + l15))*64 + g*8;
      s16x8 kh0 = *(const s16x8*)(Khb + koff);
      s16x8 kh1 = *(const s16x8*)(Khb + koff + 32);
      s16x8 kl0 = *(const s16x8*)(Klb + koff);
      s16x8 kl1 = *(const s16x8*)(Klb + koff + 32);
      f32x4 acc = {0.f,0.f,0.f,0.f};
      acc = __builtin_amdgcn_mfma_f32_16x16x32_bf16(qh0, kl0, acc, 0, 0, 0);
      acc = __builtin_amdgcn_mfma_f32_16x16x32_bf16(qh1, kl1, acc, 0, 0, 0);
      acc = __builtin_amdgcn_mfma_f32_16x16x32_bf16(ql0, kh0, acc, 0, 0, 0);
      acc = __builtin_amdgcn_mfma_f32_16x16x32_bf16(ql1, kh1, acc, 0, 0, 0);
      acc = __builtin_amdgcn_mfma_f32_16x16x32_bf16(qh0, kh0, acc, 0, 0, 0);
      acc = __builtin_amdgcn_mfma_f32_16x16x32_bf16(qh1, kh1, acc, 0, 0, 0);
      s[ct] = acc;
    }
    // ---- online softmax (per q-row r; 16-lane xor reduce over cols) ----
    #pragma unroll
    for (int r=0;r<4;++r){
      float v = fmaxf(fmaxf(s[0][r], s[1][r]), fmaxf(s[2][r], s[3][r]));
      v = fmaxf(v, __shfl_xor(v, 1));
      v = fmaxf(v, __shfl_xor(v, 2));
      v = fmaxf(v, __shfl_xor(v, 4));
      v = fmaxf(v, __shfl_xor(v, 8));
      float mn = fmaxf(m_run[r], v);
      float sc = __expf(m_run[r] - mn);
      m_run[r] = mn;
      float rs = 0.f;
      #pragma unroll
      for (int ct=0; ct<4; ++ct){
        float p = __expf(s[ct][r] - mn);
        s[ct][r] = p;
        rs += p;
      }
      rs += __shfl_xor(rs, 1);
      rs += __shfl_xor(rs, 2);
      rs += __shfl_xor(rs, 4);
      rs += __shfl_xor(rs, 8);
      l_run[r] = l_run[r]*sc + rs;
      #pragma unroll
      for (int ot=0;ot<4;++ot) o_acc[ot][r] *= sc;
    }
    // ---- P (bf16) -> swizzled LDS ----
    #pragma unroll
    for (int ct=0; ct<4; ++ct){
      #pragma unroll
      for (int r=0;r<4;++r){
        int row = g*4 + r;                 // q-row
        int col = ct*16 + l15;             // key within tile
        int off = ((row << 7) + (col << 1)) ^ ((row & 7) << 4);
        *(ushort*)((char*)pw + off) = f2bf(s[ct][r]);
      }
    }
    __syncthreads();
    // ---- P A-fragments back from LDS ----
    s16x8 pf0, pf1;
    {
      int base = (l15 << 7) + (g << 4);    // (row=l15)*128B + (k=g*8)*2B
      int swz  = (l15 & 7) << 4;
      pf0 = *(const s16x8*)((char*)pw + (base ^ swz));
      pf1 = *(const s16x8*)((char*)pw + ((base + 64) ^ swz));
    }
    // ---- O += P V ----
    #pragma unroll
    for (int ot=0; ot<4; ++ot){
      const ushort* vp = Vb + ((size_t)(ot*16 + l15))*4096 + kv + g*8;
      s16x8 v0 = *(const s16x8*)(vp);
      s16x8 v1 = *(const s16x8*)(vp + 32);
      o_acc[ot] = __builtin_amdgcn_mfma_f32_16x16x32_bf16(pf0, v0, o_acc[ot], 0,0,0);
      o_acc[ot] = __builtin_amdgcn_mfma_f32_16x16x32_bf16(pf1, v1, o_acc[ot], 0,0,0);
    }
    __syncthreads();
  }

  // ---- normalize, write O[b][n][o] f32 ----
  float* Ob = O + ((size_t)(b*4096 + qrow))*64;
  #pragma unroll
  for (int r=0;r<4;++r){
    float inv = 1.0f / l_run[r];
    #pragma unroll
    for (int ot=0;ot<4;++ot){
      Ob[(size_t)(g*4 + r)*64 + ot*16 + l15] = o_acc[ot][r] * inv;
    }
  }
}

// ---------------------------------------------------------------------------
// Kernel C: y = wc·O + bc -> BN -> ReLU -> + img. Block = (b, 64-pixel tile).
// ---------------------------------------------------------------------------
__global__ __launch_bounds__(256) void final_proj(
    const float* __restrict__ O, const float* __restrict__ wc,
    const float* __restrict__ bc, const float* __restrict__ gm,
    const float* __restrict__ bt, const float* __restrict__ mu,
    const float* __restrict__ vr, const float* __restrict__ img,
    float* __restrict__ out)
{
  __shared__ float ol[64*64];            // 16 KB
  const int tid = threadIdx.x;
  const int b  = blockIdx.x >> 6;
  const int n0 = (blockIdx.x & 63) << 6;
  const float* Ob = O + ((size_t)(b*4096) + n0)*64;

  for (int j=0;j<16;++j){
    int flat = tid + (j << 8);           // 4096 dwords, [n][o]
    int n = flat >> 6, o = flat & 63;
    ol[(o << 6) + (n ^ (o & 31))] = Ob[flat];
  }
  __syncthreads();

  const int lane = tid & 63;                                // = pixel
  const int w = __builtin_amdgcn_readfirstlane(tid >> 6);
  const int c0 = w*32;

  float acc[32];
  #pragma unroll
  for (int cc=0;cc<32;++cc) acc[cc] = 0.f;

  for (int o=0;o<64;++o){
    float v = ol[(o << 6) + (lane ^ (o & 31))];
    #pragma unroll
    for (int cc=0;cc<32;++cc)
      acc[cc] = fmaf(wc[(c0+cc)*64 + o], v, acc[cc]);       // wc uniform -> s_load
  }

  #pragma unroll
  for (int cc=0;cc<32;++cc){
    int c = c0 + cc;
    float inv = gm[c] * rsqrtf(vr[c] + 1e-5f);
    float sh  = bt[c] - mu[c]*inv;
    float y = (acc[cc] + bc[c]) * inv + sh;
    y = fmaxf(y, 0.f);
    size_t gi = ((size_t)(b*128 + c))*4096 + n0 + lane;     // 256 B coalesced
    out[gi] = img[gi] + y;
  }
}

// ---------------------------------------------------------------------------
extern "C" void kernel_launch(void* const* d_in, const int* in_sizes, int n_in,
                              void* d_out, int out_size, void* d_ws, size_t ws_size,
                              hipStream_t stream)
{
  const float* xr = (const float*)d_in[0];
  const float* xi = (const float*)d_in[1];
  const float* wq = (const float*)d_in[2];
  const float* bq = (const float*)d_in[3];
  const float* wk = (const float*)d_in[4];
  const float* bk = (const float*)d_in[5];
  const float* wv = (const float*)d_in[6];
  const float* bv = (const float*)d_in[7];
  const float* wc = (const float*)d_in[8];
  const float* bc = (const float*)d_in[9];
  const float* gm = (const float*)d_in[10];
  const float* bt = (const float*)d_in[11];
  const float* mu = (const float*)d_in[12];
  const float* vr = (const float*)d_in[13];
  float* out = (float*)d_out;

  // workspace: Qh,Ql,Kh,Kl (2MB each) + Vt (2MB) bf16 + O (4MB) f32 = 14 MB
  const size_t SZ = (size_t)4*4096*64;
  ushort* Qhw = (ushort*)d_ws;
  ushort* Qlw = Qhw + SZ;
  ushort* Khw = Qlw + SZ;
  ushort* Klw = Khw + SZ;
  ushort* Vtw = Klw + SZ;
  float*  Ow  = (float*)(Vtw + SZ);

  proj_qkv  <<<256, 256, 0, stream>>>(xr, xi, wq, bq, wk, bk, wv, bv,
                                      Qhw, Qlw, Khw, Klw, Vtw);
  flash_attn<<<256, 256, 0, stream>>>(Qhw, Qlw, Khw, Klw, Vtw, Ow);
  final_proj<<<256, 256, 0, stream>>>(Ow, wc, bc, gm, bt, mu, vr, xi, out);
}

// Round 3
// 318.421 us; speedup vs baseline: 1.2605x; 1.2605x over previous
//
#include <hip/hip_runtime.h>
#include <hip/hip_bf16.h>

typedef __attribute__((ext_vector_type(4))) float f32x4;
typedef __attribute__((ext_vector_type(8))) short s16x8;

__device__ __forceinline__ ushort f2bf(float f){
  union { float f; unsigned u; } x; x.f = f;
  unsigned r = x.u + 0x7fffu + ((x.u >> 16) & 1u);
  return (ushort)(r >> 16);
}
__device__ __forceinline__ float bf2f(ushort h){
  union { unsigned u; float f; } x; x.u = ((unsigned)h) << 16;
  return x.f;
}

// ---------------------------------------------------------------------------
// Kernel A: Q/K/V projections, fp32 weights. Grid 1024 = b(4) x ntile(64) x
//  out-quarter(4). lane = pixel, wave = 4 outputs. Q,K -> bf16 hi/lo [n][o]
//  (via small LDS transpose); V -> [o][n] coalesced. V rows 64..79 hold the
//  ones-column tile used by flash to accumulate the softmax denominator.
// ---------------------------------------------------------------------------
__global__ __launch_bounds__(256) void proj_qkv(
    const float* __restrict__ xr, const float* __restrict__ xi,
    const float* __restrict__ wq, const float* __restrict__ bq,
    const float* __restrict__ wk, const float* __restrict__ bk,
    const float* __restrict__ wv, const float* __restrict__ bv,
    ushort* __restrict__ Qh, ushort* __restrict__ Ql,
    ushort* __restrict__ Kh, ushort* __restrict__ Kl,
    ushort* __restrict__ Vt)
{
  __shared__ ushort tA[64][18];
  __shared__ ushort tB[64][18];
  const int tid = threadIdx.x;
  const int idx = blockIdx.x;
  const int oq  = idx & 3;
  const int nt  = (idx >> 2) & 63;
  const int b   = idx >> 8;
  const int n0  = nt << 6;
  const int lane = tid & 63;
  const int w    = tid >> 6;
  const int ob   = w << 2;                    // block-local o base 0,4,8,12
  const int og   = (oq << 4) + ob;            // global o base for this wave

  const float* xrb = xr + (size_t)b*128*4096 + n0 + lane;
  const float* xib = xi + (size_t)b*128*4096 + n0 + lane;

  float aq[4], ak[4], av[4];
  #pragma unroll
  for (int oo=0;oo<4;++oo){ aq[oo]=0.f; ak[oo]=0.f; av[oo]=0.f; }

  for (int c = 0; c < 128; ++c){
    float rv = xrb[c*4096];                   // 256B coalesced per wave
    float iv = xib[c*4096];
    #pragma unroll
    for (int oo=0;oo<4;++oo){
      aq[oo] = fmaf(wq[(og+oo)*128 + c], rv, aq[oo]);   // uniform -> s_load
      ak[oo] = fmaf(wk[(og+oo)*128 + c], iv, ak[oo]);
      av[oo] = fmaf(wv[(og+oo)*128 + c], iv, av[oo]);
    }
  }

  // V: coalesced [o][n] stores (80-row layout per batch)
  #pragma unroll
  for (int oo=0;oo<4;++oo)
    Vt[((size_t)b*80 + og+oo)*4096 + n0 + lane] = f2bf(av[oo] + bv[og+oo]);

  // ones/zero tail rows for the denominator tile
  if (oq == 0){
    #pragma unroll
    for (int j=0;j<4;++j){
      int row = 64 + (w<<2) + j;
      Vt[((size_t)b*80 + row)*4096 + n0 + lane] = (row==64) ? (ushort)0x3F80 : (ushort)0;
    }
  }

  // ---- Q: hi/lo via LDS transpose, vectorized [n][o] stores ----
  #pragma unroll
  for (int oo=0;oo<4;++oo){
    float q = aq[oo] + bq[og+oo];
    ushort hi = f2bf(q);
    tA[lane][ob+oo] = hi;
    tB[lane][ob+oo] = f2bf(q - bf2f(hi));
  }
  __syncthreads();
  {
    int n = tid >> 2, o0 = (tid & 3) << 2;
    ushort4 vh, vl;
    vh.x=tA[n][o0+0]; vh.y=tA[n][o0+1]; vh.z=tA[n][o0+2]; vh.w=tA[n][o0+3];
    vl.x=tB[n][o0+0]; vl.y=tB[n][o0+1]; vl.z=tB[n][o0+2]; vl.w=tB[n][o0+3];
    size_t doff = (size_t)(b*4096 + n0 + n)*64 + (oq<<4) + o0;
    *(ushort4*)(Qh + doff) = vh;
    *(ushort4*)(Ql + doff) = vl;
  }
  __syncthreads();
  // ---- K: same ----
  #pragma unroll
  for (int oo=0;oo<4;++oo){
    float k = ak[oo] + bk[og+oo];
    ushort hi = f2bf(k);
    tA[lane][ob+oo] = hi;
    tB[lane][ob+oo] = f2bf(k - bf2f(hi));
  }
  __syncthreads();
  {
    int n = tid >> 2, o0 = (tid & 3) << 2;
    ushort4 vh, vl;
    vh.x=tA[n][o0+0]; vh.y=tA[n][o0+1]; vh.z=tA[n][o0+2]; vh.w=tA[n][o0+3];
    vl.x=tB[n][o0+0]; vl.y=tB[n][o0+1]; vl.z=tB[n][o0+2]; vl.w=tB[n][o0+3];
    size_t doff = (size_t)(b*4096 + n0 + n)*64 + (oq<<4) + o0;
    *(ushort4*)(Kh + doff) = vh;
    *(ushort4*)(Kl + doff) = vl;
  }
}

// ---------------------------------------------------------------------------
// Kernel B: flash attention, KV-split x4. Grid 1024 = b(4) x qtile(64) x ks(4).
//  Block = 64-row Q tile, 4 waves x 16 rows, kv range of 1024 (16 iters).
//  No block barriers (P tile is wave-private). Denominator accumulated via
//  the V ones-column tile (o_acc[4]). Writes unnormalized partial O + (m,l).
// ---------------------------------------------------------------------------
__global__ __launch_bounds__(256, 4) void flash_attn(
    const ushort* __restrict__ Qh, const ushort* __restrict__ Ql,
    const ushort* __restrict__ Kh, const ushort* __restrict__ Kl,
    const ushort* __restrict__ Vt, float* __restrict__ Opart,
    float* __restrict__ Mst, float* __restrict__ Lst)
{
  __shared__ ushort p_lds[4][16*64];     // per-wave 16x64 bf16 P tile, swizzled
  const int tid  = threadIdx.x;
  const int idx  = blockIdx.x;
  const int ks   = idx & 3;
  const int qt   = (idx >> 2) & 63;
  const int b    = idx >> 8;
  const int lane = tid & 63;
  const int w    = tid >> 6;
  const int l15  = lane & 15;
  const int g    = lane >> 4;
  const int qrow = qt*64 + w*16;
  const int kv0  = ks << 10;

  const size_t qoff = ((size_t)(b*4096 + qrow + l15))*64 + g*8;
  s16x8 qh0 = *(const s16x8*)(Qh + qoff);
  s16x8 qh1 = *(const s16x8*)(Qh + qoff + 32);
  s16x8 ql0 = *(const s16x8*)(Ql + qoff);
  s16x8 ql1 = *(const s16x8*)(Ql + qoff + 32);

  const ushort* Khb = Kh + (size_t)b*4096*64;
  const ushort* Klb = Kl + (size_t)b*4096*64;
  const ushort* Vb  = Vt + (size_t)b*80*4096;

  f32x4 o_acc[5];
  #pragma unroll
  for (int ot=0;ot<5;++ot) o_acc[ot] = (f32x4){0.f,0.f,0.f,0.f};
  float m_run[4];
  #pragma unroll
  for (int r=0;r<4;++r) m_run[r] = -1e30f;

  ushort* pw = p_lds[w];

  for (int kv = kv0; kv < kv0 + 1024; kv += 64){
    // ---- S = Q K^T (16 x 64), hi/lo split ----
    f32x4 s[4];
    #pragma unroll
    for (int ct=0; ct<4; ++ct){
      size_t koff = ((size_t)(kv + ct*16 + l15))*64 + g*8;
      s16x8 kh0 = *(const s16x8*)(Khb + koff);
      s16x8 kh1 = *(const s16x8*)(Khb + koff + 32);
      s16x8 kl0 = *(const s16x8*)(Klb + koff);
      s16x8 kl1 = *(const s16x8*)(Klb + koff + 32);
      f32x4 acc = {0.f,0.f,0.f,0.f};
      acc = __builtin_amdgcn_mfma_f32_16x16x32_bf16(qh0, kl0, acc, 0, 0, 0);
      acc = __builtin_amdgcn_mfma_f32_16x16x32_bf16(qh1, kl1, acc, 0, 0, 0);
      acc = __builtin_amdgcn_mfma_f32_16x16x32_bf16(ql0, kh0, acc, 0, 0, 0);
      acc = __builtin_amdgcn_mfma_f32_16x16x32_bf16(ql1, kh1, acc, 0, 0, 0);
      acc = __builtin_amdgcn_mfma_f32_16x16x32_bf16(qh0, kh0, acc, 0, 0, 0);
      acc = __builtin_amdgcn_mfma_f32_16x16x32_bf16(qh1, kh1, acc, 0, 0, 0);
      s[ct] = acc;
    }
    // ---- online softmax: max-reduce only (denominator via ones tile) ----
    #pragma unroll
    for (int r=0;r<4;++r){
      float v = fmaxf(fmaxf(s[0][r], s[1][r]), fmaxf(s[2][r], s[3][r]));
      v = fmaxf(v, __shfl_xor(v, 1));
      v = fmaxf(v, __shfl_xor(v, 2));
      v = fmaxf(v, __shfl_xor(v, 4));
      v = fmaxf(v, __shfl_xor(v, 8));
      float mn = fmaxf(m_run[r], v);
      float sc = __expf(m_run[r] - mn);
      m_run[r] = mn;
      #pragma unroll
      for (int ct=0; ct<4; ++ct) s[ct][r] = __expf(s[ct][r] - mn);
      #pragma unroll
      for (int ot=0;ot<5;++ot) o_acc[ot][r] *= sc;
    }
    // ---- P (bf16) -> swizzled wave-private LDS ----
    #pragma unroll
    for (int ct=0; ct<4; ++ct){
      #pragma unroll
      for (int r=0;r<4;++r){
        int row = g*4 + r;
        int col = ct*16 + l15;
        int off = ((row << 7) + (col << 1)) ^ ((row & 7) << 4);
        *(ushort*)((char*)pw + off) = f2bf(s[ct][r]);
      }
    }
    // ---- P A-fragments back (same-wave DS ordering guarantees safety) ----
    s16x8 pf0, pf1;
    {
      int base = (l15 << 7) + (g << 4);
      int swz  = (l15 & 7) << 4;
      pf0 = *(const s16x8*)((char*)pw + (base ^ swz));
      pf1 = *(const s16x8*)((char*)pw + ((base + 64) ^ swz));
    }
    // ---- O += P V (ot=4 is the ones tile -> denominator) ----
    #pragma unroll
    for (int ot=0; ot<5; ++ot){
      const ushort* vp = Vb + ((size_t)(ot*16 + l15))*4096 + kv + g*8;
      s16x8 v0 = *(const s16x8*)(vp);
      s16x8 v1 = *(const s16x8*)(vp + 32);
      o_acc[ot] = __builtin_amdgcn_mfma_f32_16x16x32_bf16(pf0, v0, o_acc[ot], 0,0,0);
      o_acc[ot] = __builtin_amdgcn_mfma_f32_16x16x32_bf16(pf1, v1, o_acc[ot], 0,0,0);
    }
  }

  // ---- write partial O (unnormalized) + stats ----
  float* Ob = Opart + ((size_t)(ks*4 + b)*4096 + qrow)*64;
  #pragma unroll
  for (int r=0;r<4;++r){
    #pragma unroll
    for (int ot=0;ot<4;++ot)
      Ob[(size_t)(g*4 + r)*64 + ot*16 + l15] = o_acc[ot][r];
  }
  if (l15 == 0){
    float* Mb = Mst + (size_t)(ks*4 + b)*4096 + qrow;
    float* Lb = Lst + (size_t)(ks*4 + b)*4096 + qrow;
    #pragma unroll
    for (int r=0;r<4;++r){
      Mb[g*4 + r] = m_run[r];
      Lb[g*4 + r] = o_acc[4][r];
    }
  }
}

// ---------------------------------------------------------------------------
// Kernel C: merge KV-split partials, then y = wc*O+bc -> BN -> ReLU -> +img.
//  Grid 1024 = b(4) x ntile(64) x cquarter(4). Wave = 8 channels.
// ---------------------------------------------------------------------------
__global__ __launch_bounds__(256) void final_proj(
    const float* __restrict__ Opart, const float* __restrict__ Mst,
    const float* __restrict__ Lst, const float* __restrict__ wc,
    const float* __restrict__ bc, const float* __restrict__ gm,
    const float* __restrict__ bt, const float* __restrict__ mu,
    const float* __restrict__ vr, const float* __restrict__ img,
    float* __restrict__ out)
{
  __shared__ float ol[64*64];            // 16 KB
  __shared__ float scl[4][64];
  const int tid = threadIdx.x;
  const int idx = blockIdx.x;
  const int cs  = idx & 3;
  const int nt  = (idx >> 2) & 63;
  const int b   = idx >> 8;
  const int n0  = nt << 6;

  // per-row merge coefficients: scl[s][n] = exp(m_s - m*) / l*
  if (tid < 64){
    size_t rid = (size_t)b*4096 + n0 + tid;
    float m0 = Mst[0*16384 + rid], m1 = Mst[1*16384 + rid];
    float m2 = Mst[2*16384 + rid], m3 = Mst[3*16384 + rid];
    float mm = fmaxf(fmaxf(m0,m1), fmaxf(m2,m3));
    float s0 = __expf(m0-mm), s1 = __expf(m1-mm);
    float s2 = __expf(m2-mm), s3 = __expf(m3-mm);
    float li = s0*Lst[0*16384+rid] + s1*Lst[1*16384+rid]
             + s2*Lst[2*16384+rid] + s3*Lst[3*16384+rid];
    float inv = 1.0f / li;
    scl[0][tid] = s0*inv; scl[1][tid] = s1*inv;
    scl[2][tid] = s2*inv; scl[3][tid] = s3*inv;
  }
  __syncthreads();

  // merge partials -> swizzled-transposed LDS tile ol[o][n]
  {
    const size_t base = ((size_t)b*4096 + n0)*64;
    for (int j=0;j<16;++j){
      int flat = tid + (j << 8);
      int n = flat >> 6, o = flat & 63;
      float v = Opart[0*(size_t)16384*64 + base + flat] * scl[0][n]
              + Opart[1*(size_t)16384*64 + base + flat] * scl[1][n]
              + Opart[2*(size_t)16384*64 + base + flat] * scl[2][n]
              + Opart[3*(size_t)16384*64 + base + flat] * scl[3][n];
      ol[(o << 6) + (n ^ (o & 31))] = v;
    }
  }
  __syncthreads();

  const int lane = tid & 63;                                // = pixel
  const int w = __builtin_amdgcn_readfirstlane(tid >> 6);
  const int c0 = (cs << 5) + (w << 3);                      // 8 channels/wave

  float acc[8];
  #pragma unroll
  for (int cc=0;cc<8;++cc) acc[cc] = 0.f;

  for (int o=0;o<64;++o){
    float v = ol[(o << 6) + (lane ^ (o & 31))];
    #pragma unroll
    for (int cc=0;cc<8;++cc)
      acc[cc] = fmaf(wc[(c0+cc)*64 + o], v, acc[cc]);       // uniform -> s_load
  }

  #pragma unroll
  for (int cc=0;cc<8;++cc){
    int c = c0 + cc;
    float inv = gm[c] * rsqrtf(vr[c] + 1e-5f);
    float sh  = bt[c] - mu[c]*inv;
    float y = (acc[cc] + bc[c]) * inv + sh;
    y = fmaxf(y, 0.f);
    size_t gi = ((size_t)(b*128 + c))*4096 + n0 + lane;     // 256B coalesced
    out[gi] = img[gi] + y;
  }
}

// ---------------------------------------------------------------------------
extern "C" void kernel_launch(void* const* d_in, const int* in_sizes, int n_in,
                              void* d_out, int out_size, void* d_ws, size_t ws_size,
                              hipStream_t stream)
{
  const float* xr = (const float*)d_in[0];
  const float* xi = (const float*)d_in[1];
  const float* wq = (const float*)d_in[2];
  const float* bq = (const float*)d_in[3];
  const float* wk = (const float*)d_in[4];
  const float* bk = (const float*)d_in[5];
  const float* wv = (const float*)d_in[6];
  const float* bv = (const float*)d_in[7];
  const float* wc = (const float*)d_in[8];
  const float* bc = (const float*)d_in[9];
  const float* gm = (const float*)d_in[10];
  const float* bt = (const float*)d_in[11];
  const float* mu = (const float*)d_in[12];
  const float* vr = (const float*)d_in[13];
  float* out = (float*)d_out;

  // ws: Qh,Ql,Kh,Kl (2MB each) + Vt 80-row (2.5MB) + Opart 16MB + stats 0.5MB
  const size_t SZ = (size_t)4*4096*64;
  ushort* Qhw = (ushort*)d_ws;
  ushort* Qlw = Qhw + SZ;
  ushort* Khw = Qlw + SZ;
  ushort* Klw = Khw + SZ;
  ushort* Vtw = Klw + SZ;
  float*  Ow  = (float*)(Vtw + (size_t)4*80*4096);
  float*  Mw  = Ow + (size_t)16*4096*64;
  float*  Lw  = Mw + (size_t)16*4096;

  proj_qkv  <<<1024, 256, 0, stream>>>(xr, xi, wq, bq, wk, bk, wv, bv,
                                       Qhw, Qlw, Khw, Klw, Vtw);
  flash_attn<<<1024, 256, 0, stream>>>(Qhw, Qlw, Khw, Klw, Vtw, Ow, Mw, Lw);
  final_proj<<<1024, 256, 0, stream>>>(Ow, Mw, Lw, wc, bc, gm, bt, mu, vr, xi, out);
}

// Round 4
// 195.023 us; speedup vs baseline: 2.0580x; 1.6327x over previous
//
#include <hip/hip_runtime.h>
#include <hip/hip_bf16.h>

typedef __attribute__((ext_vector_type(4))) float f32x4;
typedef __attribute__((ext_vector_type(8))) short s16x8;

__device__ __forceinline__ ushort f2bf(float f){
  union { float f; unsigned u; } x; x.f = f;
  unsigned r = x.u + 0x7fffu + ((x.u >> 16) & 1u);
  return (ushort)(r >> 16);
}
__device__ __forceinline__ float bf2f(ushort h){
  union { unsigned u; float f; } x; x.u = ((unsigned)h) << 16;
  return x.f;
}

__device__ __forceinline__ void gload16(const void* g, void* l){
  __builtin_amdgcn_global_load_lds(
      (const __attribute__((address_space(1))) void*)g,
      (__attribute__((address_space(3))) void*)l, 16, 0, 0);
}

// ---------------------------------------------------------------------------
// Kernel A: Q/K/V projections, fp32 weights. Grid 1024 = b(4) x ntile(64) x
//  out-quarter(4). lane = pixel, wave = 4 outputs. Q,K -> bf16 hi/lo [n][o]
//  (via small LDS transpose); V -> [o][n] coalesced (64 rows, no tail).
// ---------------------------------------------------------------------------
__global__ __launch_bounds__(256) void proj_qkv(
    const float* __restrict__ xr, const float* __restrict__ xi,
    const float* __restrict__ wq, const float* __restrict__ bq,
    const float* __restrict__ wk, const float* __restrict__ bk,
    const float* __restrict__ wv, const float* __restrict__ bv,
    ushort* __restrict__ Qh, ushort* __restrict__ Ql,
    ushort* __restrict__ Kh, ushort* __restrict__ Kl,
    ushort* __restrict__ Vt)
{
  __shared__ ushort tA[64][18];
  __shared__ ushort tB[64][18];
  const int tid = threadIdx.x;
  const int idx = blockIdx.x;
  const int oq  = idx & 3;
  const int nt  = (idx >> 2) & 63;
  const int b   = idx >> 8;
  const int n0  = nt << 6;
  const int lane = tid & 63;
  const int w    = tid >> 6;
  const int ob   = w << 2;                    // block-local o base 0,4,8,12
  const int og   = (oq << 4) + ob;            // global o base for this wave

  const float* xrb = xr + (size_t)b*128*4096 + n0 + lane;
  const float* xib = xi + (size_t)b*128*4096 + n0 + lane;

  float aq[4], ak[4], av[4];
  #pragma unroll
  for (int oo=0;oo<4;++oo){ aq[oo]=0.f; ak[oo]=0.f; av[oo]=0.f; }

  for (int c = 0; c < 128; ++c){
    float rv = xrb[c*4096];                   // 256B coalesced per wave
    float iv = xib[c*4096];
    #pragma unroll
    for (int oo=0;oo<4;++oo){
      aq[oo] = fmaf(wq[(og+oo)*128 + c], rv, aq[oo]);   // uniform -> s_load
      ak[oo] = fmaf(wk[(og+oo)*128 + c], iv, ak[oo]);
      av[oo] = fmaf(wv[(og+oo)*128 + c], iv, av[oo]);
    }
  }

  // V: coalesced [o][n] stores
  #pragma unroll
  for (int oo=0;oo<4;++oo)
    Vt[((size_t)b*64 + og+oo)*4096 + n0 + lane] = f2bf(av[oo] + bv[og+oo]);

  // ---- Q: hi/lo via LDS transpose, vectorized [n][o] stores ----
  #pragma unroll
  for (int oo=0;oo<4;++oo){
    float q = aq[oo] + bq[og+oo];
    ushort hi = f2bf(q);
    tA[lane][ob+oo] = hi;
    tB[lane][ob+oo] = f2bf(q - bf2f(hi));
  }
  __syncthreads();
  {
    int n = tid >> 2, o0 = (tid & 3) << 2;
    ushort4 vh, vl;
    vh.x=tA[n][o0+0]; vh.y=tA[n][o0+1]; vh.z=tA[n][o0+2]; vh.w=tA[n][o0+3];
    vl.x=tB[n][o0+0]; vl.y=tB[n][o0+1]; vl.z=tB[n][o0+2]; vl.w=tB[n][o0+3];
    size_t doff = (size_t)(b*4096 + n0 + n)*64 + (oq<<4) + o0;
    *(ushort4*)(Qh + doff) = vh;
    *(ushort4*)(Ql + doff) = vl;
  }
  __syncthreads();
  // ---- K: same ----
  #pragma unroll
  for (int oo=0;oo<4;++oo){
    float k = ak[oo] + bk[og+oo];
    ushort hi = f2bf(k);
    tA[lane][ob+oo] = hi;
    tB[lane][ob+oo] = f2bf(k - bf2f(hi));
  }
  __syncthreads();
  {
    int n = tid >> 2, o0 = (tid & 3) << 2;
    ushort4 vh, vl;
    vh.x=tA[n][o0+0]; vh.y=tA[n][o0+1]; vh.z=tA[n][o0+2]; vh.w=tA[n][o0+3];
    vl.x=tB[n][o0+0]; vl.y=tB[n][o0+1]; vl.z=tB[n][o0+2]; vl.w=tB[n][o0+3];
    size_t doff = (size_t)(b*4096 + n0 + n)*64 + (oq<<4) + o0;
    *(ushort4*)(Kh + doff) = vh;
    *(ushort4*)(Kl + doff) = vl;
  }
}

// ---------------------------------------------------------------------------
// Kernel B: flash attention, KV-split x4, LDS-staged K/V shared by 4 waves.
//  Grid 1024 = b(4) x qtile(64) x ks(4). 16 iters of 64 kv.
//  LDS: Kh 8K (single), Kl 8K (single), V 2x8K (dbuf), P 4x2K = 40KB.
//  Tiles staged via global_load_lds w16 into fragment-linear layout
//  [ct][half][l15][g] -> every ds_read_b128 is a linear 1KB wave read.
//  Pipeline: QK -> B1 -> stage(t+1) -> softmax/P/PV -> B2(vmcnt drain).
//  Denominator via in-register ones B-fragment (lane l15==0 holds 1.0).
// ---------------------------------------------------------------------------
__global__ __launch_bounds__(256, 4) void flash_attn(
    const ushort* __restrict__ Qh, const ushort* __restrict__ Ql,
    const ushort* __restrict__ Kh, const ushort* __restrict__ Kl,
    const ushort* __restrict__ Vt, float* __restrict__ Opart,
    float* __restrict__ Mst, float* __restrict__ Lst)
{
  __shared__ __align__(16) ushort khL[4096];      // 8KB
  __shared__ __align__(16) ushort klL[4096];      // 8KB
  __shared__ __align__(16) ushort vL[2][4096];    // 16KB
  __shared__ __align__(16) ushort pL[4][1024];    // 8KB

  const int tid  = threadIdx.x;
  const int idx  = blockIdx.x;
  const int ks   = idx & 3;
  const int qt   = (idx >> 2) & 63;
  const int b    = idx >> 8;
  const int lane = tid & 63;
  const int w    = tid >> 6;
  const int l15  = lane & 15;
  const int g    = lane >> 4;
  const int qrow = qt*64 + w*16;
  const int kv0  = ks << 10;
  const int srow = lane >> 2;       // staging: row within 16-row sub-tile
  const int sg   = lane & 3;        // staging: 16B chunk within 64B half-row

  const size_t qoff = ((size_t)(b*4096 + qrow + l15))*64 + g*8;
  s16x8 qh0 = *(const s16x8*)(Qh + qoff);
  s16x8 qh1 = *(const s16x8*)(Qh + qoff + 32);
  s16x8 ql0 = *(const s16x8*)(Ql + qoff);
  s16x8 ql1 = *(const s16x8*)(Ql + qoff + 32);

  const char* KhB = (const char*)(Kh + (size_t)b*4096*64);
  const char* KlB = (const char*)(Kl + (size_t)b*4096*64);
  const char* VB  = (const char*)(Vt + (size_t)b*64*4096);

  // ones B-fragment: B[k][col]=1 iff col==0 -> lane l15==0 holds 8x bf16 1.0
  s16x8 ones;
  #pragma unroll
  for (int e=0;e<8;++e) ones[e] = (l15==0) ? (short)0x3F80 : (short)0;

  f32x4 o_acc[5];
  #pragma unroll
  for (int ot=0;ot<5;++ot) o_acc[ot] = (f32x4){0.f,0.f,0.f,0.f};
  float m_run[4];
  #pragma unroll
  for (int r=0;r<4;++r) m_run[r] = -1e30f;

  ushort* pw = pL[w];

  // ---- staging: wave w stages rows [w*16, w*16+16) of each tile ----
  // K tile (row-major 128B rows): LDS sub-block (ct=w, h) at w*2048 + h*1024.
  // V tile ([o][n], 8192B rows): same sub-block structure.
  #define STAGE_KV(kvb, vdst)                                             \
  {                                                                       \
    size_t kr = (size_t)((kvb) + w*16 + srow)*128 + sg*16;                \
    char* kd = (char*)khL + w*2048;                                       \
    gload16(KhB + kr,      kd);                                           \
    gload16(KhB + kr + 64, kd + 1024);                                    \
    char* ld = (char*)klL + w*2048;                                       \
    gload16(KlB + kr,      ld);                                           \
    gload16(KlB + kr + 64, ld + 1024);                                    \
    size_t vr = (size_t)(w*16 + srow)*8192 + (size_t)(kvb)*2 + sg*16;     \
    char* vd = (char*)(vdst) + w*2048;                                    \
    gload16(VB + vr,      vd);                                            \
    gload16(VB + vr + 64, vd + 1024);                                     \
  }

  STAGE_KV(kv0, vL[0]);
  __syncthreads();                       // drains vmcnt -> tile 0 resident

  const int fragoff = l15*64 + g*16;     // byte offset of lane's fragment

  for (int t = 0; t < 16; ++t){
    const char* vcur = (const char*)vL[t & 1];
    // ---- S = Q K^T (16 x 64), hi/lo split, K from LDS ----
    f32x4 s[4];
    #pragma unroll
    for (int ct=0; ct<4; ++ct){
      const char* kb = (const char*)khL + ct*2048;
      const char* lb = (const char*)klL + ct*2048;
      s16x8 kh0 = *(const s16x8*)(kb + fragoff);
      s16x8 kh1 = *(const s16x8*)(kb + 1024 + fragoff);
      s16x8 kl0 = *(const s16x8*)(lb + fragoff);
      s16x8 kl1 = *(const s16x8*)(lb + 1024 + fragoff);
      f32x4 acc = {0.f,0.f,0.f,0.f};
      acc = __builtin_amdgcn_mfma_f32_16x16x32_bf16(qh0, kl0, acc, 0, 0, 0);
      acc = __builtin_amdgcn_mfma_f32_16x16x32_bf16(qh1, kl1, acc, 0, 0, 0);
      acc = __builtin_amdgcn_mfma_f32_16x16x32_bf16(ql0, kh0, acc, 0, 0, 0);
      acc = __builtin_amdgcn_mfma_f32_16x16x32_bf16(ql1, kh1, acc, 0, 0, 0);
      acc = __builtin_amdgcn_mfma_f32_16x16x32_bf16(qh0, kh0, acc, 0, 0, 0);
      acc = __builtin_amdgcn_mfma_f32_16x16x32_bf16(qh1, kh1, acc, 0, 0, 0);
      s[ct] = acc;
    }
    __syncthreads();                     // B1: Kh/Kl free for restage

    if (t < 15){
      int kvn = kv0 + (t+1)*64;
      STAGE_KV(kvn, vL[(t & 1) ^ 1]);    // async; drained at B2
    }

    // ---- online softmax: max-reduce only ----
    #pragma unroll
    for (int r=0;r<4;++r){
      float v = fmaxf(fmaxf(s[0][r], s[1][r]), fmaxf(s[2][r], s[3][r]));
      v = fmaxf(v, __shfl_xor(v, 1));
      v = fmaxf(v, __shfl_xor(v, 2));
      v = fmaxf(v, __shfl_xor(v, 4));
      v = fmaxf(v, __shfl_xor(v, 8));
      float mn = fmaxf(m_run[r], v);
      float sc = __expf(m_run[r] - mn);
      m_run[r] = mn;
      #pragma unroll
      for (int ct=0; ct<4; ++ct) s[ct][r] = __expf(s[ct][r] - mn);
      #pragma unroll
      for (int ot=0;ot<5;++ot) o_acc[ot][r] *= sc;
    }
    // ---- P (bf16) -> swizzled wave-private LDS ----
    #pragma unroll
    for (int ct=0; ct<4; ++ct){
      #pragma unroll
      for (int r=0;r<4;++r){
        int row = g*4 + r;
        int col = ct*16 + l15;
        int off = ((row << 7) + (col << 1)) ^ ((row & 7) << 4);
        *(ushort*)((char*)pw + off) = f2bf(s[ct][r]);
      }
    }
    // ---- P A-fragments back (same-wave DS ordering) ----
    s16x8 pf0, pf1;
    {
      int base = (l15 << 7) + (g << 4);
      int swz  = (l15 & 7) << 4;
      pf0 = *(const s16x8*)((char*)pw + (base ^ swz));
      pf1 = *(const s16x8*)((char*)pw + ((base + 64) ^ swz));
    }
    // ---- O += P V (V from LDS; denominator via ones frag) ----
    #pragma unroll
    for (int ot=0; ot<4; ++ot){
      const char* vb = vcur + ot*2048;
      s16x8 v0 = *(const s16x8*)(vb + fragoff);
      s16x8 v1 = *(const s16x8*)(vb + 1024 + fragoff);
      o_acc[ot] = __builtin_amdgcn_mfma_f32_16x16x32_bf16(pf0, v0, o_acc[ot], 0,0,0);
      o_acc[ot] = __builtin_amdgcn_mfma_f32_16x16x32_bf16(pf1, v1, o_acc[ot], 0,0,0);
    }
    o_acc[4] = __builtin_amdgcn_mfma_f32_16x16x32_bf16(pf0, ones, o_acc[4], 0,0,0);
    o_acc[4] = __builtin_amdgcn_mfma_f32_16x16x32_bf16(pf1, ones, o_acc[4], 0,0,0);

    __syncthreads();                     // B2: drains vmcnt -> tile t+1 ready
  }
  #undef STAGE_KV

  // ---- write partial O (unnormalized) + stats ----
  float* Ob = Opart + ((size_t)(ks*4 + b)*4096 + qrow)*64;
  #pragma unroll
  for (int r=0;r<4;++r){
    #pragma unroll
    for (int ot=0;ot<4;++ot)
      Ob[(size_t)(g*4 + r)*64 + ot*16 + l15] = o_acc[ot][r];
  }
  if (l15 == 0){
    float* Mb = Mst + (size_t)(ks*4 + b)*4096 + qrow;
    float* Lb = Lst + (size_t)(ks*4 + b)*4096 + qrow;
    #pragma unroll
    for (int r=0;r<4;++r){
      Mb[g*4 + r] = m_run[r];
      Lb[g*4 + r] = o_acc[4][r];
    }
  }
}

// ---------------------------------------------------------------------------
// Kernel C: merge KV-split partials, then y = wc*O+bc -> BN -> ReLU -> +img.
//  Grid 1024 = b(4) x ntile(64) x cquarter(4). Wave = 8 channels.
// ---------------------------------------------------------------------------
__global__ __launch_bounds__(256) void final_proj(
    const float* __restrict__ Opart, const float* __restrict__ Mst,
    const float* __restrict__ Lst, const float* __restrict__ wc,
    const float* __restrict__ bc, const float* __restrict__ gm,
    const float* __restrict__ bt, const float* __restrict__ mu,
    const float* __restrict__ vr, const float* __restrict__ img,
    float* __restrict__ out)
{
  __shared__ float ol[64*64];            // 16 KB
  __shared__ float scl[4][64];
  const int tid = threadIdx.x;
  const int idx = blockIdx.x;
  const int cs  = idx & 3;
  const int nt  = (idx >> 2) & 63;
  const int b   = idx >> 8;
  const int n0  = nt << 6;

  // per-row merge coefficients: scl[s][n] = exp(m_s - m*) / l*
  if (tid < 64){
    size_t rid = (size_t)b*4096 + n0 + tid;
    float m0 = Mst[0*16384 + rid], m1 = Mst[1*16384 + rid];
    float m2 = Mst[2*16384 + rid], m3 = Mst[3*16384 + rid];
    float mm = fmaxf(fmaxf(m0,m1), fmaxf(m2,m3));
    float s0 = __expf(m0-mm), s1 = __expf(m1-mm);
    float s2 = __expf(m2-mm), s3 = __expf(m3-mm);
    float li = s0*Lst[0*16384+rid] + s1*Lst[1*16384+rid]
             + s2*Lst[2*16384+rid] + s3*Lst[3*16384+rid];
    float inv = 1.0f / li;
    scl[0][tid] = s0*inv; scl[1][tid] = s1*inv;
    scl[2][tid] = s2*inv; scl[3][tid] = s3*inv;
  }
  __syncthreads();

  // merge partials -> swizzled-transposed LDS tile ol[o][n]
  {
    const size_t base = ((size_t)b*4096 + n0)*64;
    for (int j=0;j<16;++j){
      int flat = tid + (j << 8);
      int n = flat >> 6, o = flat & 63;
      float v = Opart[0*(size_t)16384*64 + base + flat] * scl[0][n]
              + Opart[1*(size_t)16384*64 + base + flat] * scl[1][n]
              + Opart[2*(size_t)16384*64 + base + flat] * scl[2][n]
              + Opart[3*(size_t)16384*64 + base + flat] * scl[3][n];
      ol[(o << 6) + (n ^ (o & 31))] = v;
    }
  }
  __syncthreads();

  const int lane = tid & 63;                                // = pixel
  const int w = __builtin_amdgcn_readfirstlane(tid >> 6);
  const int c0 = (cs << 5) + (w << 3);                      // 8 channels/wave

  float acc[8];
  #pragma unroll
  for (int cc=0;cc<8;++cc) acc[cc] = 0.f;

  for (int o=0;o<64;++o){
    float v = ol[(o << 6) + (lane ^ (o & 31))];
    #pragma unroll
    for (int cc=0;cc<8;++cc)
      acc[cc] = fmaf(wc[(c0+cc)*64 + o], v, acc[cc]);       // uniform -> s_load
  }

  #pragma unroll
  for (int cc=0;cc<8;++cc){
    int c = c0 + cc;
    float inv = gm[c] * rsqrtf(vr[c] + 1e-5f);
    float sh  = bt[c] - mu[c]*inv;
    float y = (acc[cc] + bc[c]) * inv + sh;
    y = fmaxf(y, 0.f);
    size_t gi = ((size_t)(b*128 + c))*4096 + n0 + lane;     // 256B coalesced
    out[gi] = img[gi] + y;
  }
}

// ---------------------------------------------------------------------------
extern "C" void kernel_launch(void* const* d_in, const int* in_sizes, int n_in,
                              void* d_out, int out_size, void* d_ws, size_t ws_size,
                              hipStream_t stream)
{
  const float* xr = (const float*)d_in[0];
  const float* xi = (const float*)d_in[1];
  const float* wq = (const float*)d_in[2];
  const float* bq = (const float*)d_in[3];
  const float* wk = (const float*)d_in[4];
  const float* bk = (const float*)d_in[5];
  const float* wv = (const float*)d_in[6];
  const float* bv = (const float*)d_in[7];
  const float* wc = (const float*)d_in[8];
  const float* bc = (const float*)d_in[9];
  const float* gm = (const float*)d_in[10];
  const float* bt = (const float*)d_in[11];
  const float* mu = (const float*)d_in[12];
  const float* vr = (const float*)d_in[13];
  float* out = (float*)d_out;

  // ws: Qh,Ql,Kh,Kl (2MB each) + Vt (2MB) + Opart 16MB + stats 0.5MB
  const size_t SZ = (size_t)4*4096*64;
  ushort* Qhw = (ushort*)d_ws;
  ushort* Qlw = Qhw + SZ;
  ushort* Khw = Qlw + SZ;
  ushort* Klw = Khw + SZ;
  ushort* Vtw = Klw + SZ;
  float*  Ow  = (float*)(Vtw + SZ);
  float*  Mw  = Ow + (size_t)16*4096*64;
  float*  Lw  = Mw + (size_t)16*4096;

  proj_qkv  <<<1024, 256, 0, stream>>>(xr, xi, wq, bq, wk, bk, wv, bv,
                                       Qhw, Qlw, Khw, Klw, Vtw);
  flash_attn<<<1024, 256, 0, stream>>>(Qhw, Qlw, Khw, Klw, Vtw, Ow, Mw, Lw);
  final_proj<<<1024, 256, 0, stream>>>(Ow, Mw, Lw, wc, bc, gm, bt, mu, vr, xi, out);
}

// Round 5
// 109.435 us; speedup vs baseline: 3.6676x; 1.7821x over previous
//
#include <hip/hip_runtime.h>
#include <hip/hip_bf16.h>

typedef __attribute__((ext_vector_type(4))) float f32x4;
typedef __attribute__((ext_vector_type(8))) short s16x8;

__device__ __forceinline__ ushort f2bf(float f){
  union { float f; unsigned u; } x; x.f = f;
  unsigned r = x.u + 0x7fffu + ((x.u >> 16) & 1u);
  return (ushort)(r >> 16);
}
__device__ __forceinline__ float bf2f(ushort h){
  union { unsigned u; float f; } x; x.u = ((unsigned)h) << 16;
  return x.f;
}

__device__ __forceinline__ void gload16(const void* g, void* l){
  __builtin_amdgcn_global_load_lds(
      (const __attribute__((address_space(1))) void*)g,
      (__attribute__((address_space(3))) void*)l, 16, 0, 0);
}

// ---------------------------------------------------------------------------
// Kernel W: one-time weight prep. wq/wk/wv f32 [64][128] -> Wh/Wl bf16
//  [192][128] (rows 0-63 q, 64-127 k, 128-191 v). L2-resident, 96 KB.
// ---------------------------------------------------------------------------
__global__ __launch_bounds__(256) void wprep(
    const float* __restrict__ wq, const float* __restrict__ wk,
    const float* __restrict__ wv, ushort* __restrict__ Wh,
    ushort* __restrict__ Wl)
{
  int flat = blockIdx.x*256 + threadIdx.x;        // 0..24575
  int row = flat >> 7, c = flat & 127;
  float v = (row < 64) ? wq[row*128 + c]
          : (row < 128) ? wk[(row-64)*128 + c]
          : wv[(row-128)*128 + c];
  ushort hi = f2bf(v);
  Wh[flat] = hi;
  Wl[flat] = f2bf(v - bf2f(hi));
}

// ---------------------------------------------------------------------------
// Kernel A: MFMA Q/K/V projections. Grid 512 = b(4) x ntile(64) x ohalf(2).
//  Block: 64 px, 96 outputs (32 q + 32 k + 32 v). Wave = 16-px tile.
//  x tile [128c][64px] f32 staged via global_load_lds (linear). Each wave
//  builds hi/lo bf16 x-fragments once, then streams weight fragments from
//  global (bf16, L1/L2-hit) through 72 MFMAs.
//  Q,K: D[px][o] = mfma(a=x, b=w) -> [n][o] layout, fp32 acc split hi/lo.
//  V:   D[o][px] = mfma(a=w, b=x) -> [o][n] layout directly.
// ---------------------------------------------------------------------------
__global__ __launch_bounds__(256, 2) void proj_qkv(
    const float* __restrict__ xr, const float* __restrict__ xi,
    const ushort* __restrict__ Wh, const ushort* __restrict__ Wl,
    const float* __restrict__ bq, const float* __restrict__ bk,
    const float* __restrict__ bv,
    ushort* __restrict__ Qh, ushort* __restrict__ Ql,
    ushort* __restrict__ Kh, ushort* __restrict__ Kl,
    ushort* __restrict__ Vt)
{
  __shared__ __align__(16) float xrL[128*64];     // 32 KB
  __shared__ __align__(16) float xiL[128*64];     // 32 KB
  const int tid = threadIdx.x;
  const int idx = blockIdx.x;
  const int oh  = idx & 1;
  const int nt  = (idx >> 1) & 63;
  const int b   = idx >> 7;
  const int n0  = nt << 6;
  const int lane = tid & 63;
  const int w    = tid >> 6;
  const int l15  = lane & 15;
  const int g    = lane >> 4;

  // ---- stage x tiles [128][64] f32, linear dest ----
  {
    const float* xrs = xr + (size_t)b*524288 + n0;
    const float* xis = xi + (size_t)b*524288 + n0;
    #pragma unroll
    for (int j = 0; j < 8; ++j){
      int row = j*16 + (tid >> 4);
      int ch  = tid & 15;
      gload16(xrs + (size_t)row*4096 + ch*4, xrL + j*1024 + w*256);
      gload16(xis + (size_t)row*4096 + ch*4, xiL + j*1024 + w*256);
    }
  }
  __syncthreads();

  // ---- build hi/lo A-fragments of x (lane l15 = px, g*8 = k-chunk) ----
  s16x8 xrh[4], xrl[4], xih[4], xil[4];
  const int px = w*16 + l15;
  #pragma unroll
  for (int kc = 0; kc < 4; ++kc){
    #pragma unroll
    for (int j = 0; j < 8; ++j){
      int r = kc*32 + g*8 + j;
      float a = xrL[r*64 + px];
      ushort h = f2bf(a);
      xrh[kc][j] = (short)h;
      xrl[kc][j] = (short)f2bf(a - bf2f(h));
      float bb = xiL[r*64 + px];
      ushort h2 = f2bf(bb);
      xih[kc][j] = (short)h2;
      xil[kc][j] = (short)f2bf(bb - bf2f(h2));
    }
  }

  // ---- 6 output tiles: q0,q1,k0,k1,v0,v1 (16 outs each) ----
  #pragma unroll
  for (int ot = 0; ot < 6; ++ot){
    const int p    = ot >> 1;                     // 0=q 1=k 2=v
    const int sub  = ot & 1;
    const int obase = oh*32 + sub*16;             // o within [0,64)
    const int wrow  = p*64 + obase;               // row in Wh/Wl [192][128]
    f32x4 acc = {0.f,0.f,0.f,0.f};
    #pragma unroll
    for (int kc = 0; kc < 4; ++kc){
      s16x8 whf = *(const s16x8*)(Wh + (size_t)(wrow + l15)*128 + kc*32 + g*8);
      s16x8 wlf = *(const s16x8*)(Wl + (size_t)(wrow + l15)*128 + kc*32 + g*8);
      const s16x8 xh = (p==0) ? xrh[kc] : xih[kc];
      const s16x8 xl = (p==0) ? xrl[kc] : xil[kc];
      if (p < 2){
        acc = __builtin_amdgcn_mfma_f32_16x16x32_bf16(xh, whf, acc, 0,0,0);
        acc = __builtin_amdgcn_mfma_f32_16x16x32_bf16(xl, whf, acc, 0,0,0);
        acc = __builtin_amdgcn_mfma_f32_16x16x32_bf16(xh, wlf, acc, 0,0,0);
      } else {
        acc = __builtin_amdgcn_mfma_f32_16x16x32_bf16(whf, xh, acc, 0,0,0);
        acc = __builtin_amdgcn_mfma_f32_16x16x32_bf16(wlf, xh, acc, 0,0,0);
        acc = __builtin_amdgcn_mfma_f32_16x16x32_bf16(whf, xl, acc, 0,0,0);
      }
    }
    if (p == 0){
      float bqv = bq[obase + l15];
      #pragma unroll
      for (int r = 0; r < 4; ++r){
        float q = acc[r] + bqv;
        ushort hi = f2bf(q);
        size_t a = (size_t)(b*4096 + n0 + w*16 + g*4 + r)*64 + obase + l15;
        Qh[a] = hi; Ql[a] = f2bf(q - bf2f(hi));
      }
    } else if (p == 1){
      float bkv = bk[obase + l15];
      #pragma unroll
      for (int r = 0; r < 4; ++r){
        float k = acc[r] + bkv;
        ushort hi = f2bf(k);
        size_t a = (size_t)(b*4096 + n0 + w*16 + g*4 + r)*64 + obase + l15;
        Kh[a] = hi; Kl[a] = f2bf(k - bf2f(hi));
      }
    } else {
      #pragma unroll
      for (int r = 0; r < 4; ++r){
        int o = obase + g*4 + r;
        float v = acc[r] + bv[o];
        Vt[(size_t)(b*64 + o)*4096 + n0 + w*16 + l15] = f2bf(v);
      }
    }
  }
}

// ---------------------------------------------------------------------------
// Kernel B: flash attention, KV-split x4, LDS-staged K/V shared by 4 waves.
//  Grid 1024 = b(4) x qtile(64) x ks(4). 16 iters of 64 kv.
// ---------------------------------------------------------------------------
__global__ __launch_bounds__(256, 4) void flash_attn(
    const ushort* __restrict__ Qh, const ushort* __restrict__ Ql,
    const ushort* __restrict__ Kh, const ushort* __restrict__ Kl,
    const ushort* __restrict__ Vt, float* __restrict__ Opart,
    float* __restrict__ Mst, float* __restrict__ Lst)
{
  __shared__ __align__(16) ushort khL[4096];      // 8KB
  __shared__ __align__(16) ushort klL[4096];      // 8KB
  __shared__ __align__(16) ushort vL[2][4096];    // 16KB
  __shared__ __align__(16) ushort pL[4][1024];    // 8KB

  const int tid  = threadIdx.x;
  const int idx  = blockIdx.x;
  const int ks   = idx & 3;
  const int qt   = (idx >> 2) & 63;
  const int b    = idx >> 8;
  const int lane = tid & 63;
  const int w    = tid >> 6;
  const int l15  = lane & 15;
  const int g    = lane >> 4;
  const int qrow = qt*64 + w*16;
  const int kv0  = ks << 10;
  const int srow = lane >> 2;
  const int sg   = lane & 3;

  const size_t qoff = ((size_t)(b*4096 + qrow + l15))*64 + g*8;
  s16x8 qh0 = *(const s16x8*)(Qh + qoff);
  s16x8 qh1 = *(const s16x8*)(Qh + qoff + 32);
  s16x8 ql0 = *(const s16x8*)(Ql + qoff);
  s16x8 ql1 = *(const s16x8*)(Ql + qoff + 32);

  const char* KhB = (const char*)(Kh + (size_t)b*4096*64);
  const char* KlB = (const char*)(Kl + (size_t)b*4096*64);
  const char* VB  = (const char*)(Vt + (size_t)b*64*4096);

  s16x8 ones;
  #pragma unroll
  for (int e=0;e<8;++e) ones[e] = (l15==0) ? (short)0x3F80 : (short)0;

  f32x4 o_acc[5];
  #pragma unroll
  for (int ot=0;ot<5;++ot) o_acc[ot] = (f32x4){0.f,0.f,0.f,0.f};
  float m_run[4];
  #pragma unroll
  for (int r=0;r<4;++r) m_run[r] = -1e30f;

  ushort* pw = pL[w];

  #define STAGE_KV(kvb, vdst)                                             \
  {                                                                       \
    size_t kr = (size_t)((kvb) + w*16 + srow)*128 + sg*16;                \
    char* kd = (char*)khL + w*2048;                                       \
    gload16(KhB + kr,      kd);                                           \
    gload16(KhB + kr + 64, kd + 1024);                                    \
    char* ld = (char*)klL + w*2048;                                       \
    gload16(KlB + kr,      ld);                                           \
    gload16(KlB + kr + 64, ld + 1024);                                    \
    size_t vr = (size_t)(w*16 + srow)*8192 + (size_t)(kvb)*2 + sg*16;     \
    char* vd = (char*)(vdst) + w*2048;                                    \
    gload16(VB + vr,      vd);                                            \
    gload16(VB + vr + 64, vd + 1024);                                     \
  }

  STAGE_KV(kv0, vL[0]);
  __syncthreads();

  const int fragoff = l15*64 + g*16;

  for (int t = 0; t < 16; ++t){
    const char* vcur = (const char*)vL[t & 1];
    f32x4 s[4];
    #pragma unroll
    for (int ct=0; ct<4; ++ct){
      const char* kb = (const char*)khL + ct*2048;
      const char* lb = (const char*)klL + ct*2048;
      s16x8 kh0 = *(const s16x8*)(kb + fragoff);
      s16x8 kh1 = *(const s16x8*)(kb + 1024 + fragoff);
      s16x8 kl0 = *(const s16x8*)(lb + fragoff);
      s16x8 kl1 = *(const s16x8*)(lb + 1024 + fragoff);
      f32x4 acc = {0.f,0.f,0.f,0.f};
      acc = __builtin_amdgcn_mfma_f32_16x16x32_bf16(qh0, kl0, acc, 0, 0, 0);
      acc = __builtin_amdgcn_mfma_f32_16x16x32_bf16(qh1, kl1, acc, 0, 0, 0);
      acc = __builtin_amdgcn_mfma_f32_16x16x32_bf16(ql0, kh0, acc, 0, 0, 0);
      acc = __builtin_amdgcn_mfma_f32_16x16x32_bf16(ql1, kh1, acc, 0, 0, 0);
      acc = __builtin_amdgcn_mfma_f32_16x16x32_bf16(qh0, kh0, acc, 0, 0, 0);
      acc = __builtin_amdgcn_mfma_f32_16x16x32_bf16(qh1, kh1, acc, 0, 0, 0);
      s[ct] = acc;
    }
    __syncthreads();

    if (t < 15){
      int kvn = kv0 + (t+1)*64;
      STAGE_KV(kvn, vL[(t & 1) ^ 1]);
    }

    #pragma unroll
    for (int r=0;r<4;++r){
      float v = fmaxf(fmaxf(s[0][r], s[1][r]), fmaxf(s[2][r], s[3][r]));
      v = fmaxf(v, __shfl_xor(v, 1));
      v = fmaxf(v, __shfl_xor(v, 2));
      v = fmaxf(v, __shfl_xor(v, 4));
      v = fmaxf(v, __shfl_xor(v, 8));
      float mn = fmaxf(m_run[r], v);
      float sc = __expf(m_run[r] - mn);
      m_run[r] = mn;
      #pragma unroll
      for (int ct=0; ct<4; ++ct) s[ct][r] = __expf(s[ct][r] - mn);
      #pragma unroll
      for (int ot=0;ot<5;++ot) o_acc[ot][r] *= sc;
    }
    #pragma unroll
    for (int ct=0; ct<4; ++ct){
      #pragma unroll
      for (int r=0;r<4;++r){
        int row = g*4 + r;
        int col = ct*16 + l15;
        int off = ((row << 7) + (col << 1)) ^ ((row & 7) << 4);
        *(ushort*)((char*)pw + off) = f2bf(s[ct][r]);
      }
    }
    s16x8 pf0, pf1;
    {
      int base = (l15 << 7) + (g << 4);
      int swz  = (l15 & 7) << 4;
      pf0 = *(const s16x8*)((char*)pw + (base ^ swz));
      pf1 = *(const s16x8*)((char*)pw + ((base + 64) ^ swz));
    }
    #pragma unroll
    for (int ot=0; ot<4; ++ot){
      const char* vb = vcur + ot*2048;
      s16x8 v0 = *(const s16x8*)(vb + fragoff);
      s16x8 v1 = *(const s16x8*)(vb + 1024 + fragoff);
      o_acc[ot] = __builtin_amdgcn_mfma_f32_16x16x32_bf16(pf0, v0, o_acc[ot], 0,0,0);
      o_acc[ot] = __builtin_amdgcn_mfma_f32_16x16x32_bf16(pf1, v1, o_acc[ot], 0,0,0);
    }
    o_acc[4] = __builtin_amdgcn_mfma_f32_16x16x32_bf16(pf0, ones, o_acc[4], 0,0,0);
    o_acc[4] = __builtin_amdgcn_mfma_f32_16x16x32_bf16(pf1, ones, o_acc[4], 0,0,0);

    __syncthreads();
  }
  #undef STAGE_KV

  float* Ob = Opart + ((size_t)(ks*4 + b)*4096 + qrow)*64;
  #pragma unroll
  for (int r=0;r<4;++r){
    #pragma unroll
    for (int ot=0;ot<4;++ot)
      Ob[(size_t)(g*4 + r)*64 + ot*16 + l15] = o_acc[ot][r];
  }
  if (l15 == 0){
    float* Mb = Mst + (size_t)(ks*4 + b)*4096 + qrow;
    float* Lb = Lst + (size_t)(ks*4 + b)*4096 + qrow;
    #pragma unroll
    for (int r=0;r<4;++r){
      Mb[g*4 + r] = m_run[r];
      Lb[g*4 + r] = o_acc[4][r];
    }
  }
}

// ---------------------------------------------------------------------------
// Kernel C: merge KV-split partials, then y = wc*O+bc -> BN -> ReLU -> +img.
// ---------------------------------------------------------------------------
__global__ __launch_bounds__(256) void final_proj(
    const float* __restrict__ Opart, const float* __restrict__ Mst,
    const float* __restrict__ Lst, const float* __restrict__ wc,
    const float* __restrict__ bc, const float* __restrict__ gm,
    const float* __restrict__ bt, const float* __restrict__ mu,
    const float* __restrict__ vr, const float* __restrict__ img,
    float* __restrict__ out)
{
  __shared__ float ol[64*64];
  __shared__ float scl[4][64];
  const int tid = threadIdx.x;
  const int idx = blockIdx.x;
  const int cs  = idx & 3;
  const int nt  = (idx >> 2) & 63;
  const int b   = idx >> 8;
  const int n0  = nt << 6;

  if (tid < 64){
    size_t rid = (size_t)b*4096 + n0 + tid;
    float m0 = Mst[0*16384 + rid], m1 = Mst[1*16384 + rid];
    float m2 = Mst[2*16384 + rid], m3 = Mst[3*16384 + rid];
    float mm = fmaxf(fmaxf(m0,m1), fmaxf(m2,m3));
    float s0 = __expf(m0-mm), s1 = __expf(m1-mm);
    float s2 = __expf(m2-mm), s3 = __expf(m3-mm);
    float li = s0*Lst[0*16384+rid] + s1*Lst[1*16384+rid]
             + s2*Lst[2*16384+rid] + s3*Lst[3*16384+rid];
    float inv = 1.0f / li;
    scl[0][tid] = s0*inv; scl[1][tid] = s1*inv;
    scl[2][tid] = s2*inv; scl[3][tid] = s3*inv;
  }
  __syncthreads();

  {
    const size_t base = ((size_t)b*4096 + n0)*64;
    for (int j=0;j<16;++j){
      int flat = tid + (j << 8);
      int n = flat >> 6, o = flat & 63;
      float v = Opart[0*(size_t)16384*64 + base + flat] * scl[0][n]
              + Opart[1*(size_t)16384*64 + base + flat] * scl[1][n]
              + Opart[2*(size_t)16384*64 + base + flat] * scl[2][n]
              + Opart[3*(size_t)16384*64 + base + flat] * scl[3][n];
      ol[(o << 6) + (n ^ (o & 31))] = v;
    }
  }
  __syncthreads();

  const int lane = tid & 63;
  const int w = __builtin_amdgcn_readfirstlane(tid >> 6);
  const int c0 = (cs << 5) + (w << 3);

  float acc[8];
  #pragma unroll
  for (int cc=0;cc<8;++cc) acc[cc] = 0.f;

  for (int o=0;o<64;++o){
    float v = ol[(o << 6) + (lane ^ (o & 31))];
    #pragma unroll
    for (int cc=0;cc<8;++cc)
      acc[cc] = fmaf(wc[(c0+cc)*64 + o], v, acc[cc]);
  }

  #pragma unroll
  for (int cc=0;cc<8;++cc){
    int c = c0 + cc;
    float inv = gm[c] * rsqrtf(vr[c] + 1e-5f);
    float sh  = bt[c] - mu[c]*inv;
    float y = (acc[cc] + bc[c]) * inv + sh;
    y = fmaxf(y, 0.f);
    size_t gi = ((size_t)(b*128 + c))*4096 + n0 + lane;
    out[gi] = img[gi] + y;
  }
}

// ---------------------------------------------------------------------------
extern "C" void kernel_launch(void* const* d_in, const int* in_sizes, int n_in,
                              void* d_out, int out_size, void* d_ws, size_t ws_size,
                              hipStream_t stream)
{
  const float* xr = (const float*)d_in[0];
  const float* xi = (const float*)d_in[1];
  const float* wq = (const float*)d_in[2];
  const float* bq = (const float*)d_in[3];
  const float* wk = (const float*)d_in[4];
  const float* bk = (const float*)d_in[5];
  const float* wv = (const float*)d_in[6];
  const float* bv = (const float*)d_in[7];
  const float* wc = (const float*)d_in[8];
  const float* bc = (const float*)d_in[9];
  const float* gm = (const float*)d_in[10];
  const float* bt = (const float*)d_in[11];
  const float* mu = (const float*)d_in[12];
  const float* vr = (const float*)d_in[13];
  float* out = (float*)d_out;

  const size_t SZ = (size_t)4*4096*64;
  ushort* Qhw = (ushort*)d_ws;
  ushort* Qlw = Qhw + SZ;
  ushort* Khw = Qlw + SZ;
  ushort* Klw = Khw + SZ;
  ushort* Vtw = Klw + SZ;
  float*  Ow  = (float*)(Vtw + SZ);
  float*  Mw  = Ow + (size_t)16*4096*64;
  float*  Lw  = Mw + (size_t)16*4096;
  ushort* Whb = (ushort*)(Lw + (size_t)16*4096);
  ushort* Wlb = Whb + 192*128;

  wprep     <<<96,   256, 0, stream>>>(wq, wk, wv, Whb, Wlb);
  proj_qkv  <<<512,  256, 0, stream>>>(xr, xi, Whb, Wlb, bq, bk, bv,
                                       Qhw, Qlw, Khw, Klw, Vtw);
  flash_attn<<<1024, 256, 0, stream>>>(Qhw, Qlw, Khw, Klw, Vtw, Ow, Mw, Lw);
  final_proj<<<1024, 256, 0, stream>>>(Ow, Mw, Lw, wc, bc, gm, bt, mu, vr, xi, out);
}